// Round 7
// baseline (202.119 us; speedup 1.0000x reference)
//
#include <hip/hip_runtime.h>
#include <math.h>

#define BDIM 2
#define NSEQ 2048
#define DMODEL 512
#define NH 8
#define DH 64
#define INNER (NH * DH)          // 512
#define QKV_COLS (3 * INNER)     // 1536
#define MROWS (BDIM * NSEQ)      // 4096
#define C2 0.180336879f          // 64^-0.5 * log2(e)

typedef short bf16x8 __attribute__((ext_vector_type(8)));
typedef float f32x4 __attribute__((ext_vector_type(4)));

static __device__ __forceinline__ unsigned short f2bf(float f) {
    unsigned int u = __float_as_uint(f);
    unsigned int r = (u + 0x7FFFu + ((u >> 16) & 1u)) >> 16;
    return (unsigned short)r;
}
static __device__ __forceinline__ unsigned int pack2bf(float a, float b) {
    unsigned int ua = (__float_as_uint(a) + 0x8000u) >> 16;
    unsigned int ub = (__float_as_uint(b) + 0x8000u) & 0xFFFF0000u;
    return ub | ua;
}

// ---------------------------------------------------------------------------
// Merged conversions: blocks 0..1023 convert x; 1024..1215 transpose Wqkv;
// 1216..1279 transpose Wout.
// ---------------------------------------------------------------------------
__global__ __launch_bounds__(256) void conv_all_kernel(
    const float* __restrict__ x, const float* __restrict__ Wqkv,
    const float* __restrict__ Wout, unsigned short* __restrict__ xb,
    unsigned short* __restrict__ wqt, unsigned short* __restrict__ wot)
{
    __shared__ float T[64][65];
    const int t = blockIdx.x, tid = threadIdx.x;
    if (t < 1024) {
        const int base = t * 2048 + tid * 8;
        float4 a = *(const float4*)(x + base);
        float4 b = *(const float4*)(x + base + 4);
        ushort4 oa, ob;
        oa.x = f2bf(a.x); oa.y = f2bf(a.y); oa.z = f2bf(a.z); oa.w = f2bf(a.w);
        ob.x = f2bf(b.x); ob.y = f2bf(b.y); ob.z = f2bf(b.z); ob.w = f2bf(b.w);
        *(ushort4*)(xb + base) = oa;
        *(ushort4*)(xb + base + 4) = ob;
        return;
    }
    const float* W; unsigned short* Wt; int R, C, c0, r0;
    if (t < 1216) {
        const int u = t - 1024;
        W = Wqkv; Wt = wqt; R = DMODEL; C = QKV_COLS;
        c0 = (u % 24) * 64; r0 = (u / 24) * 64;
    } else {
        const int u = t - 1216;
        W = Wout; Wt = wot; R = INNER; C = DMODEL;
        c0 = (u & 7) * 64; r0 = (u >> 3) * 64;
    }
    const int tx = tid & 15, ty = tid >> 4;
#pragma unroll
    for (int i = 0; i < 4; ++i) {
        const int r = ty + i * 16;
        float4 v = *(const float4*)(W + (size_t)(r0 + r) * C + c0 + tx * 4);
        T[r][tx * 4 + 0] = v.x; T[r][tx * 4 + 1] = v.y;
        T[r][tx * 4 + 2] = v.z; T[r][tx * 4 + 3] = v.w;
    }
    __syncthreads();
#pragma unroll
    for (int i = 0; i < 4; ++i) {
        const int cc = ty + i * 16;
        ushort4 o;
        o.x = f2bf(T[tx * 4 + 0][cc]);
        o.y = f2bf(T[tx * 4 + 1][cc]);
        o.z = f2bf(T[tx * 4 + 2][cc]);
        o.w = f2bf(T[tx * 4 + 3][cc]);
        *(ushort4*)(Wt + (size_t)(c0 + cc) * R + r0 + tx * 4) = o;
    }
}

// ---------------------------------------------------------------------------
// GEMM1: xb[4096,512] @ Wqkvt[1536,512]^T -> Q,K [b][h][n][d], V^T [b][h][d][n]
// Tile 128x64 (768 blocks, 3/CU). One head per block -> simple epilogue.
// ---------------------------------------------------------------------------
__global__ __launch_bounds__(256) void gemm_qkv_kernel(
    const unsigned short* __restrict__ A, const unsigned short* __restrict__ Bt,
    unsigned short* __restrict__ Qb, unsigned short* __restrict__ Kb,
    unsigned short* __restrict__ Vtb)
{
    __shared__ short Smem[15360];   // 30720 B: staging As+Bs; epilogue Cs
    short (*As)[80] = (short (*)[80])Smem;
    short (*Bs)[80] = (short (*)[80])(Smem + 128 * 80);

    const int tid = threadIdx.x;
    const int w = tid >> 6, lane = tid & 63;
    const int lo = lane & 15, quad = lane >> 4;
    const int wm = (w & 1) * 64, wn = (w >> 1) * 32;
    const int m0 = blockIdx.y * 128, n0 = blockIdx.x * 64;

    f32x4 acc[4][2];
#pragma unroll
    for (int i = 0; i < 4; ++i)
#pragma unroll
        for (int j = 0; j < 2; ++j) acc[i][j] = (f32x4)0.0f;

    int4 ar[4], br[2];
#pragma unroll
    for (int it = 0; it < 4; ++it) {
        const int lin = it * 2048 + tid * 8;
        ar[it] = *(const int4*)(A + (size_t)(m0 + (lin >> 6)) * DMODEL + (lin & 63));
    }
#pragma unroll
    for (int it = 0; it < 2; ++it) {
        const int lin = it * 2048 + tid * 8;
        br[it] = *(const int4*)(Bt + (size_t)(n0 + (lin >> 6)) * DMODEL + (lin & 63));
    }

    for (int k0 = 0; k0 < DMODEL; k0 += 64) {
        __syncthreads();
#pragma unroll
        for (int it = 0; it < 4; ++it) {
            const int lin = it * 2048 + tid * 8;
            *(int4*)&As[lin >> 6][lin & 63] = ar[it];
        }
#pragma unroll
        for (int it = 0; it < 2; ++it) {
            const int lin = it * 2048 + tid * 8;
            *(int4*)&Bs[lin >> 6][lin & 63] = br[it];
        }
        __syncthreads();
        if (k0 + 64 < DMODEL) {
            const int kn = k0 + 64;
#pragma unroll
            for (int it = 0; it < 4; ++it) {
                const int lin = it * 2048 + tid * 8;
                ar[it] = *(const int4*)(A + (size_t)(m0 + (lin >> 6)) * DMODEL + kn + (lin & 63));
            }
#pragma unroll
            for (int it = 0; it < 2; ++it) {
                const int lin = it * 2048 + tid * 8;
                br[it] = *(const int4*)(Bt + (size_t)(n0 + (lin >> 6)) * DMODEL + kn + (lin & 63));
            }
        }
#pragma unroll
        for (int kc = 0; kc < 2; ++kc) {
            bf16x8 af[4], bf_[2];
#pragma unroll
            for (int mt = 0; mt < 4; ++mt)
                af[mt] = *(const bf16x8*)&As[wm + mt * 16 + lo][kc * 32 + quad * 8];
#pragma unroll
            for (int nt = 0; nt < 2; ++nt)
                bf_[nt] = *(const bf16x8*)&Bs[wn + nt * 16 + lo][kc * 32 + quad * 8];
#pragma unroll
            for (int mt = 0; mt < 4; ++mt)
#pragma unroll
                for (int nt = 0; nt < 2; ++nt)
                    acc[mt][nt] = __builtin_amdgcn_mfma_f32_16x16x32_bf16(
                        af[mt], bf_[nt], acc[mt][nt], 0, 0, 0);
        }
    }

    const int which = n0 >> 9;             // 0=Q 1=K 2=V
    const int h0 = (n0 & 511) >> 6;        // exactly one head per block
    const int bb = m0 >> 11, nn0 = m0 & 2047;

    __syncthreads();
    if (which < 2) {
        short (*Cs)[72] = (short (*)[72])Smem;   // [128 m][64+8 c]
#pragma unroll
        for (int mt = 0; mt < 4; ++mt)
#pragma unroll
            for (int nt = 0; nt < 2; ++nt)
#pragma unroll
                for (int r = 0; r < 4; ++r)
                    Cs[wm + mt * 16 + quad * 4 + r][wn + nt * 16 + lo] =
                        (short)f2bf(acc[mt][nt][r]);
        __syncthreads();
        unsigned short* dst0 = (which == 0 ? Qb : Kb) +
            ((size_t)(bb * NH + h0) * NSEQ + nn0) * DH;
#pragma unroll
        for (int it = 0; it < 4; ++it) {
            const int lin = it * 256 + tid;          // int4 index
            const int row = lin >> 3, c = (lin & 7) * 8;
            *(int4*)(dst0 + (size_t)row * DH + c) = *(const int4*)&Cs[row][c];
        }
    } else {
        short (*Cs)[136] = (short (*)[136])Smem;  // [64 c][128+8 m]
#pragma unroll
        for (int mt = 0; mt < 4; ++mt)
#pragma unroll
            for (int nt = 0; nt < 2; ++nt)
#pragma unroll
                for (int r = 0; r < 4; ++r)
                    Cs[wn + nt * 16 + lo][wm + mt * 16 + quad * 4 + r] =
                        (short)f2bf(acc[mt][nt][r]);
        __syncthreads();
        unsigned short* dst0 = Vtb + (size_t)(bb * NH + h0) * DH * NSEQ;
#pragma unroll
        for (int it = 0; it < 4; ++it) {
            const int lin = it * 256 + tid;
            const int c = lin >> 4, m8 = (lin & 15) * 8;
            *(int4*)(dst0 + (size_t)c * NSEQ + nn0 + m8) = *(const int4*)&Cs[c][m8];
        }
    }
}

// ---------------------------------------------------------------------------
// Flash attention (causal): ZERO LDS, ZERO barriers. One wave = 16 q-rows,
// 2-way j-split. K/V fragments loaded straight from global (L2-resident per
// head via hb%8 XCD affinity). S^T formulation + bpermute P-transform.
// ---------------------------------------------------------------------------
__global__ __launch_bounds__(256, 4) void flash_kernel(
    const unsigned short* __restrict__ Qb, const unsigned short* __restrict__ Kb,
    const unsigned short* __restrict__ Vtb, float* __restrict__ Pml,
    unsigned short* __restrict__ Po)
{
    const int tid = threadIdx.x;
    const int w = tid >> 6, lane = tid & 63;
    const int lo = lane & 15, quad = lane >> 4;
    const int hb = blockIdx.x;
    const int h = hb & 7, bb = hb >> 3;              // per-head XCD affinity
    const int sp = blockIdx.z;
    const int qraw = blockIdx.y * 4 + w;             // 0..127
    const int qt = (sp == 0) ? qraw : 127 - qraw;    // heavy/light interleave

    const unsigned short* Qg = Qb + (size_t)(bb * NH + h) * NSEQ * DH;
    const unsigned short* Kg = Kb + (size_t)(bb * NH + h) * NSEQ * DH;
    const unsigned short* Vg = Vtb + (size_t)(bb * NH + h) * DH * NSEQ;

    // Q B-frags straight to registers
    const unsigned short* qptr = Qg + (size_t)(qt * 16 + lo) * DH + quad * 8;
    const bf16x8 aq0 = *(const bf16x8*)qptr;
    const bf16x8 aq1 = *(const bf16x8*)(qptr + 32);

    const int jd = qt >> 2;                          // diagonal 64-tile
    const int nIter = (jd >= sp) ? (((jd - sp) >> 1) + 1) : 0;
    const int qrel = (qt & 3) * 16 + lo;             // q pos within diag tile

    const int addrA = ((((quad * 2) & 3) * 16 + lo) * 4);
    const int addrB = ((((quad * 2 + 1) & 3) * 16 + lo) * 4);
    const bool qlow = (quad < 2);

    f32x4 O[4];
#pragma unroll
    for (int dt = 0; dt < 4; ++dt) O[dt] = (f32x4)0.0f;
    float mrow = -INFINITY, lrow = 0.0f;

    for (int it = 0; it < nIter; ++it) {
        const int jb = sp + it * 2;
        const int j0 = jb * 64;

        // K A-frags: K[j0+nt*16+lo][kc*32+quad*8 ..+7]
        int4 kf[8];
#pragma unroll
        for (int nt = 0; nt < 4; ++nt)
#pragma unroll
            for (int kc = 0; kc < 2; ++kc)
                kf[nt * 2 + kc] = *(const int4*)(
                    Kg + (size_t)(j0 + nt * 16 + lo) * DH + kc * 32 + quad * 8);
        // V^T A-frags: Vt[dt*16+lo][j0+kc*32+quad*8 ..+7]
        int4 vf[8];
#pragma unroll
        for (int dt = 0; dt < 4; ++dt)
#pragma unroll
            for (int kc = 0; kc < 2; ++kc)
                vf[dt * 2 + kc] = *(const int4*)(
                    Vg + (size_t)(dt * 16 + lo) * NSEQ + j0 + kc * 32 + quad * 8);

        // S^T = K Q^T
        f32x4 s[4];
#pragma unroll
        for (int nt = 0; nt < 4; ++nt) s[nt] = (f32x4)0.0f;
#pragma unroll
        for (int kc = 0; kc < 2; ++kc) {
            const bf16x8 aq = kc ? aq1 : aq0;
#pragma unroll
            for (int nt = 0; nt < 4; ++nt)
                s[nt] = __builtin_amdgcn_mfma_f32_16x16x32_bf16(
                    *(const bf16x8*)&kf[nt * 2 + kc], aq, s[nt], 0, 0, 0);
        }

        if (jb == jd) {   // causal mask on the diagonal tile
#pragma unroll
            for (int nt = 0; nt < 4; ++nt)
#pragma unroll
                for (int r = 0; r < 4; ++r)
                    if (nt * 16 + quad * 4 + r > qrel) s[nt][r] = -1e30f;
        }

        // online softmax: one q-row per lane (j spread over lanes/regs)
        float rm = s[0][0];
#pragma unroll
        for (int nt = 0; nt < 4; ++nt)
#pragma unroll
            for (int r = 0; r < 4; ++r) rm = fmaxf(rm, s[nt][r]);
        rm = fmaxf(rm, __shfl_xor(rm, 16));
        rm = fmaxf(rm, __shfl_xor(rm, 32));
        const float mnew = fmaxf(mrow, rm);
        const float alpha = __builtin_exp2f((mrow - mnew) * C2);
        mrow = mnew;
        const float mc = mnew * C2;
        float rs = 0.0f;
#pragma unroll
        for (int nt = 0; nt < 4; ++nt)
#pragma unroll
            for (int r = 0; r < 4; ++r) {
                float p = __builtin_exp2f(__builtin_fmaf(s[nt][r], C2, -mc));
                s[nt][r] = p;
                rs += p;
            }
        rs += __shfl_xor(rs, 16);
        rs += __shfl_xor(rs, 32);
        lrow = alpha * lrow + rs;

#pragma unroll
        for (int dt = 0; dt < 4; ++dt)
#pragma unroll
            for (int r = 0; r < 4; ++r) O[dt][r] *= alpha;

        // P^T -> PV B-frags via lane permutation
        int pk[4][2];
#pragma unroll
        for (int nt = 0; nt < 4; ++nt) {
            pk[nt][0] = (int)pack2bf(s[nt][0], s[nt][1]);
            pk[nt][1] = (int)pack2bf(s[nt][2], s[nt][3]);
        }
#pragma unroll
        for (int kc = 0; kc < 2; ++kc) {
            int4 pbi;
            {
                int t0 = __builtin_amdgcn_ds_bpermute(addrA, pk[kc * 2 + 0][0]);
                int t1 = __builtin_amdgcn_ds_bpermute(addrA, pk[kc * 2 + 1][0]);
                pbi.x = qlow ? t0 : t1;
                t0 = __builtin_amdgcn_ds_bpermute(addrA, pk[kc * 2 + 0][1]);
                t1 = __builtin_amdgcn_ds_bpermute(addrA, pk[kc * 2 + 1][1]);
                pbi.y = qlow ? t0 : t1;
                t0 = __builtin_amdgcn_ds_bpermute(addrB, pk[kc * 2 + 0][0]);
                t1 = __builtin_amdgcn_ds_bpermute(addrB, pk[kc * 2 + 1][0]);
                pbi.z = qlow ? t0 : t1;
                t0 = __builtin_amdgcn_ds_bpermute(addrB, pk[kc * 2 + 0][1]);
                t1 = __builtin_amdgcn_ds_bpermute(addrB, pk[kc * 2 + 1][1]);
                pbi.w = qlow ? t0 : t1;
            }
            const bf16x8 pb = *(const bf16x8*)&pbi;
#pragma unroll
            for (int dt = 0; dt < 4; ++dt)
                O[dt] = __builtin_amdgcn_mfma_f32_16x16x32_bf16(
                    *(const bf16x8*)&vf[dt * 2 + kc], pb, O[dt], 0, 0, 0);
        }
    }

    // partial epilogue: m,l + self-normalized O^T (bf16) to workspace
    const int pidx = (hb * 128 + qt) * 2 + sp;
    if (quad == 0) {
        Pml[(size_t)pidx * 32 + lo] = mrow;
        Pml[(size_t)pidx * 32 + 16 + lo] = lrow;
    }
    const float inv = (lrow > 0.0f) ? 1.0f / lrow : 0.0f;
    unsigned short* po = Po + (size_t)pidx * 1024 + lo * 64 + quad * 4;
#pragma unroll
    for (int dt = 0; dt < 4; ++dt) {
        uint2 v;
        v.x = pack2bf(O[dt][0] * inv, O[dt][1] * inv);
        v.y = pack2bf(O[dt][2] * inv, O[dt][3] * inv);
        *(uint2*)(po + dt * 16) = v;
    }
}

// ---------------------------------------------------------------------------
// Combine the two j-split partials -> attnb [b][n][h*64+d] bf16.
// 1024 blocks; each handles 2 (hb,qt) groups of 16 rows x 64 d.
// ---------------------------------------------------------------------------
__global__ __launch_bounds__(256) void combine_kernel(
    const float* __restrict__ Pml, const unsigned short* __restrict__ Po,
    unsigned short* __restrict__ attnb)
{
    const int tid = threadIdx.x;
    const int g = blockIdx.x * 2 + (tid >> 7);     // hb*128 + qt
    const int hb = g >> 7, qt = g & 127;
    const int h = hb & 7, bb = hb >> 3;
    const int row = (tid >> 3) & 15, d0 = (tid & 7) * 8;

    const float* ml0 = Pml + (size_t)(g * 2) * 32;
    const float* ml1 = ml0 + 32;
    const float m0 = ml0[row], l0 = ml0[16 + row];
    const float m1 = ml1[row], l1 = ml1[16 + row];
    const float m = fmaxf(m0, m1);
    const float a0 = l0 * __builtin_exp2f((m0 - m) * C2);
    const float a1 = l1 * __builtin_exp2f((m1 - m) * C2);
    const float inv = 1.0f / (a0 + a1);
    const float c0 = a0 * inv, c1 = a1 * inv;

    const unsigned short* p0 = Po + (size_t)(g * 2) * 1024 + row * 64 + d0;
    const unsigned short* p1 = p0 + 1024;
    unsigned short sa[8], sb[8], so[8];
    *(int4*)&sa[0] = *(const int4*)p0;
    *(int4*)&sb[0] = *(const int4*)p1;
#pragma unroll
    for (int i = 0; i < 8; ++i) {
        float fa = __uint_as_float((unsigned int)sa[i] << 16);
        float fb = __uint_as_float((unsigned int)sb[i] << 16);
        so[i] = f2bf(fa * c0 + fb * c1);
    }
    unsigned short* dst = attnb + ((size_t)bb * NSEQ + qt * 16 + row) * INNER + h * DH + d0;
    *(int4*)dst = *(const int4*)&so[0];
}

// ---------------------------------------------------------------------------
// GEMM2: attnb[4096,512] @ Woutt[512,512]^T + bias -> out fp32. Tile 128x64.
// ---------------------------------------------------------------------------
__global__ __launch_bounds__(256) void gemm_out_kernel(
    const unsigned short* __restrict__ A, const unsigned short* __restrict__ Bt,
    const float* __restrict__ bias, float* __restrict__ out)
{
    __shared__ short As[128][80];
    __shared__ short Bs[64][80];

    const int tid = threadIdx.x;
    const int w = tid >> 6, lane = tid & 63;
    const int lo = lane & 15, quad = lane >> 4;
    const int wm = (w & 1) * 64, wn = (w >> 1) * 32;
    const int m0 = blockIdx.y * 128, n0 = blockIdx.x * 64;

    f32x4 acc[4][2];
#pragma unroll
    for (int i = 0; i < 4; ++i)
#pragma unroll
        for (int j = 0; j < 2; ++j) acc[i][j] = (f32x4)0.0f;

    int4 ar[4], br[2];
#pragma unroll
    for (int it = 0; it < 4; ++it) {
        const int lin = it * 2048 + tid * 8;
        ar[it] = *(const int4*)(A + (size_t)(m0 + (lin >> 6)) * INNER + (lin & 63));
    }
#pragma unroll
    for (int it = 0; it < 2; ++it) {
        const int lin = it * 2048 + tid * 8;
        br[it] = *(const int4*)(Bt + (size_t)(n0 + (lin >> 6)) * INNER + (lin & 63));
    }

    for (int k0 = 0; k0 < INNER; k0 += 64) {
        __syncthreads();
#pragma unroll
        for (int it = 0; it < 4; ++it) {
            const int lin = it * 2048 + tid * 8;
            *(int4*)&As[lin >> 6][lin & 63] = ar[it];
        }
#pragma unroll
        for (int it = 0; it < 2; ++it) {
            const int lin = it * 2048 + tid * 8;
            *(int4*)&Bs[lin >> 6][lin & 63] = br[it];
        }
        __syncthreads();
        if (k0 + 64 < INNER) {
            const int kn = k0 + 64;
#pragma unroll
            for (int it = 0; it < 4; ++it) {
                const int lin = it * 2048 + tid * 8;
                ar[it] = *(const int4*)(A + (size_t)(m0 + (lin >> 6)) * INNER + kn + (lin & 63));
            }
#pragma unroll
            for (int it = 0; it < 2; ++it) {
                const int lin = it * 2048 + tid * 8;
                br[it] = *(const int4*)(Bt + (size_t)(n0 + (lin >> 6)) * INNER + kn + (lin & 63));
            }
        }
#pragma unroll
        for (int kc = 0; kc < 2; ++kc) {
            bf16x8 af[4], bf_[2];
#pragma unroll
            for (int mt = 0; mt < 4; ++mt)
                af[mt] = *(const bf16x8*)&As[wm + mt * 16 + lo][kc * 32 + quad * 8];
#pragma unroll
            for (int nt = 0; nt < 2; ++nt)
                bf_[nt] = *(const bf16x8*)&Bs[wn + nt * 16 + lo][kc * 32 + quad * 8];
#pragma unroll
            for (int mt = 0; mt < 4; ++mt)
#pragma unroll
                for (int nt = 0; nt < 2; ++nt)
                    acc[mt][nt] = __builtin_amdgcn_mfma_f32_16x16x32_bf16(
                        af[mt], bf_[nt], acc[mt][nt], 0, 0, 0);
        }
    }

#pragma unroll
    for (int mt = 0; mt < 4; ++mt) {
        const int gm0 = m0 + wm + mt * 16 + quad * 4;
#pragma unroll
        for (int nt = 0; nt < 2; ++nt) {
            const int gc = n0 + wn + nt * 16 + lo;
            const float b = bias[gc];
#pragma unroll
            for (int r = 0; r < 4; ++r)
                out[(size_t)(gm0 + r) * DMODEL + gc] = acc[mt][nt][r] + b;
        }
    }
}

// ---------------------------------------------------------------------------
extern "C" void kernel_launch(void* const* d_in, const int* in_sizes, int n_in,
                              void* d_out, int out_size, void* d_ws, size_t ws_size,
                              hipStream_t stream) {
    const float* x    = (const float*)d_in[0];
    const float* Wqkv = (const float*)d_in[2];
    const float* Wout = (const float*)d_in[3];
    const float* bout = (const float*)d_in[4];
    float* out = (float*)d_out;

    unsigned short* wsS  = (unsigned short*)d_ws;
    unsigned short* xb   = wsS;
    unsigned short* wqt  = xb   + (size_t)MROWS * DMODEL;
    unsigned short* wot  = wqt  + (size_t)QKV_COLS * DMODEL;
    unsigned short* Qb   = wot  + (size_t)DMODEL * INNER;
    unsigned short* Kb   = Qb   + (size_t)BDIM * NH * NSEQ * DH;
    unsigned short* Vtb  = Kb   + (size_t)BDIM * NH * NSEQ * DH;
    unsigned short* attnb= Vtb  + (size_t)BDIM * NH * NSEQ * DH;
    float* Pml = (float*)(attnb + (size_t)MROWS * INNER);      // 4096*32 floats
    unsigned short* Po = (unsigned short*)(Pml + 4096 * 32);   // 4096*1024 shorts

    conv_all_kernel<<<1280, 256, 0, stream>>>(x, Wqkv, Wout, xb, wqt, wot);
    gemm_qkv_kernel<<<dim3(QKV_COLS / 64, MROWS / 128), 256, 0, stream>>>(xb, wqt, Qb, Kb, Vtb);
    flash_kernel<<<dim3(NH * BDIM, 32, 2), 256, 0, stream>>>(Qb, Kb, Vtb, Pml, Po);
    combine_kernel<<<1024, 256, 0, stream>>>(Pml, Po, attnb);
    gemm_out_kernel<<<dim3(DMODEL / 64, MROWS / 128), 256, 0, stream>>>(attnb, wot, bout, out);
}